// Round 11
// baseline (369.331 us; speedup 1.0000x reference)
//
#include <hip/hip_runtime.h>
#include <cstdint>

#define POOLK 7
#define NCLS 91
#define FH 50
#define FW 50
#define FCH 256
#define DIM (FCH * POOLK * POOLK) /* 12544 */
#define HID 1024
#define TOPK_OUT 100
#define DW_MAXF 4.135166556742356f

typedef __attribute__((ext_vector_type(8))) short short8;
typedef __attribute__((ext_vector_type(4))) float f32x4;

__device__ __forceinline__ unsigned short f2bf(float x)
{
    unsigned u = __float_as_uint(x);
    return (unsigned short)((u + 0x7FFFu + ((u >> 16) & 1u)) >> 16);
}
__device__ __forceinline__ float bf2f(unsigned short h)
{
    return __uint_as_float((unsigned)h << 16);
}

// ------------------------------- feat [C][2500] -> featT [2500][C] (f32)
__global__ __launch_bounds__(256) void ftrans_kernel(
    const float* __restrict__ feat, float* __restrict__ featT)
{
    __shared__ float tile[64][65];
    int c0 = blockIdx.x * 64;
    int p0 = blockIdx.y * 64;
    int lane = threadIdx.x & 63, r4 = threadIdx.x >> 6;
    #pragma unroll
    for (int r = r4; r < 64; r += 4) {
        int p = p0 + lane;
        if (p < FH * FW) tile[r][lane] = feat[(size_t)(c0 + r) * (FH * FW) + p];
    }
    __syncthreads();
    #pragma unroll
    for (int r = r4; r < 64; r += 4) {
        int p = p0 + r;
        if (p < FH * FW) featT[(size_t)p * FCH + c0 + lane] = tile[lane][r];
    }
}

// ---------------- ROI pool: block(512) per ROI, wave = cell, lane = 4 channels
// output layout PERMUTED: pooled[roi][cell*256 + c]  (fc1_w permuted to match)
__global__ __launch_bounds__(512) void roi_pool_kernel(
    const float* __restrict__ featT, const float* __restrict__ props,
    unsigned short* __restrict__ pooled, int n0, int rows,
    const int* __restrict__ img_h, const int* __restrict__ img_w)
{
    int rl = blockIdx.x;
    if (rl >= rows) return;
    int n = n0 + rl;
    int lane = threadIdx.x & 63;       // 4 channels: [lane*4, lane*4+4)
    int wv = threadIdx.x >> 6;         // 0..7, one cell per wave

    float scale = (float)fmin((double)FH / (double)img_h[0],
                              (double)FW / (double)img_w[0]);
    float x1 = rintf(props[n * 4 + 0] * scale);
    float y1 = rintf(props[n * 4 + 1] * scale);
    float x2 = rintf(props[n * 4 + 2] * scale);
    float y2 = rintf(props[n * 4 + 3] * scale);
    float roiw = fmaxf(x2 - x1 + 1.f, 1.f);
    float roih = fmaxf(y2 - y1 + 1.f, 1.f);

    const float4* ft4 = (const float4*)featT;
    unsigned short* orow = pooled + (size_t)rl * DIM;

    for (int cell = wv; cell < 49; cell += 8) {
        int py = cell / 7, px = cell - py * 7;
        int h0 = (int)fminf(fmaxf(floorf((float)py * roih / 7.f) + y1, 0.f), (float)FH);
        int h1 = (int)fminf(fmaxf(ceilf(((float)py + 1.f) * roih / 7.f) + y1, 0.f), (float)FH);
        int w0 = (int)fminf(fmaxf(floorf((float)px * roiw / 7.f) + x1, 0.f), (float)FW);
        int w1 = (int)fminf(fmaxf(ceilf(((float)px + 1.f) * roiw / 7.f) + x1, 0.f), (float)FW);

        float4 ma = make_float4(-INFINITY, -INFINITY, -INFINITY, -INFINITY);
        float4 mb = ma;
        for (int h = h0; h < h1; ++h) {
            const float4* rp = ft4 + (size_t)(h * FW) * 64 + lane;
            int w = w0;
            for (; w + 1 < w1; w += 2) {
                float4 va = rp[(size_t)w * 64];
                float4 vb = rp[(size_t)(w + 1) * 64];
                ma.x = fmaxf(ma.x, va.x); ma.y = fmaxf(ma.y, va.y);
                ma.z = fmaxf(ma.z, va.z); ma.w = fmaxf(ma.w, va.w);
                mb.x = fmaxf(mb.x, vb.x); mb.y = fmaxf(mb.y, vb.y);
                mb.z = fmaxf(mb.z, vb.z); mb.w = fmaxf(mb.w, vb.w);
            }
            if (w < w1) {
                float4 va = rp[(size_t)w * 64];
                ma.x = fmaxf(ma.x, va.x); ma.y = fmaxf(ma.y, va.y);
                ma.z = fmaxf(ma.z, va.z); ma.w = fmaxf(ma.w, va.w);
            }
        }
        float4 m;
        m.x = fmaxf(ma.x, mb.x); m.y = fmaxf(ma.y, mb.y);
        m.z = fmaxf(ma.z, mb.z); m.w = fmaxf(ma.w, mb.w);
        if (h0 >= h1 || w0 >= w1) m = make_float4(0.f, 0.f, 0.f, 0.f);
        ushort4 o;
        o.x = f2bf(m.x); o.y = f2bf(m.y); o.z = f2bf(m.z); o.w = f2bf(m.w);
        *(ushort4*)&orow[cell * FCH + lane * 4] = o;
    }
}

// --------------------------------------------------------- fp32 -> bf16 weights
__global__ __launch_bounds__(256) void wconv_kernel(
    const float* __restrict__ w, unsigned short* __restrict__ wh, int n4)
{
    int i = blockIdx.x * 256 + threadIdx.x;
    if (i >= n4) return;
    float4 v = ((const float4*)w)[i];
    ushort4 o;
    o.x = f2bf(v.x); o.y = f2bf(v.y); o.z = f2bf(v.z); o.w = f2bf(v.w);
    ((ushort4*)wh)[i] = o;
}

// ---- fc1_w conversion with K-permutation via LDS (coalesced both sides)
//      wh[n][cell*256 + c] = w[n][c*49 + cell]
#define PERM_PAD 257
__global__ __launch_bounds__(256) void wconv_perm_kernel(
    const float* __restrict__ w, unsigned short* __restrict__ wh)
{
    __shared__ unsigned short sh[49 * PERM_PAD];
    int n = blockIdx.x;
    const float* row = w + (size_t)n * DIM;
    #pragma unroll 7
    for (int k = 0; k < 49; ++k) {
        int j = k * 256 + threadIdx.x;     // coalesced read index = c*49 + cell
        float v = row[j];
        int c = j / 49, cell = j - c * 49;
        sh[cell * PERM_PAD + c] = f2bf(v);
    }
    __syncthreads();
    unsigned short* orow = wh + (size_t)n * DIM;
    #pragma unroll 7
    for (int k = 0; k < 49; ++k) {
        int o = k * 256 + threadIdx.x;     // coalesced write index = cell*256 + c
        int cell = o >> 8, c = o & 255;
        orow[o] = sh[cell * PERM_PAD + c];
    }
}

typedef __attribute__((address_space(1))) void* gas_p;
typedef __attribute__((address_space(3))) void* las_p;
__device__ __forceinline__ void async16(void* l, const void* g)
{
    __builtin_amdgcn_global_load_lds((gas_p)g, (las_p)l, 16, 0, 0);
}

// ------------------------------------------------- split-K MFMA bf16 GEMM 128x128
// A: M x K bf16 row-major, B(=W): N x K bf16 row-major, partials bf16
// T4-lite: counted vmcnt(8) keeps next tile's loads in flight across barrier
#define GBK 64
__global__ __launch_bounds__(256, 2) void gemm_bf16_kernel(
    const unsigned short* __restrict__ A, const unsigned short* __restrict__ B,
    unsigned short* __restrict__ part, int M, int N, int K, int ksteps, int KS)
{
    __shared__ unsigned short ldsA[2][128 * GBK];
    __shared__ unsigned short ldsB[2][128 * GBK];

    int t = threadIdx.x;
    int lane = t & 63, wave = t >> 6;
    int m0 = blockIdx.y * 128, n0 = blockIdx.x * 128;

    int steps_per = (ksteps + KS - 1) / KS;
    int ks0 = blockIdx.z * steps_per;
    int ks1 = min(ksteps, ks0 + steps_per);
    int nt = ks1 - ks0;

    int lrow  = lane >> 3;
    int lslot = (lane & 7) ^ lrow;     // pre-swizzled global source slot
    const unsigned short* aSrc[4];
    const unsigned short* bSrc[4];
    #pragma unroll
    for (int i = 0; i < 4; ++i) {
        int r = wave * 32 + i * 8 + lrow;
        int gm = min(m0 + r, M - 1);
        int gn = min(n0 + r, N - 1);
        aSrc[i] = A + (size_t)gm * K + lslot * 8;
        bSrc[i] = B + (size_t)gn * K + lslot * 8;
    }

    int wr = wave >> 1, wc = wave & 1;   // 2x2 waves, each owns 64x64
    int fr = lane & 15, fq = lane >> 4;

    f32x4 acc[4][4] = {};

    auto STAGE = [&](int buf, int kt) {
        int koff = kt * GBK;
        #pragma unroll
        for (int i = 0; i < 4; ++i) {
            async16(&ldsA[buf][(wave * 32 + i * 8) * GBK], aSrc[i] + koff);
            async16(&ldsB[buf][(wave * 32 + i * 8) * GBK], bSrc[i] + koff);
        }
    };

    auto COMPUTE = [&](int buf) {
        #pragma unroll
        for (int h = 0; h < 2; ++h) {
            short8 af[4], bfr[4];
            #pragma unroll
            for (int mi = 0; mi < 4; ++mi) {
                int r = wr * 64 + mi * 16 + fr;
                int idx = r * GBK + (((h * 4 + fq) ^ (r & 7)) << 3);
                af[mi] = *(const short8*)&ldsA[buf][idx];
            }
            #pragma unroll
            for (int ni = 0; ni < 4; ++ni) {
                int r = wc * 64 + ni * 16 + fr;
                int idx = r * GBK + (((h * 4 + fq) ^ (r & 7)) << 3);
                bfr[ni] = *(const short8*)&ldsB[buf][idx];
            }
            #pragma unroll
            for (int mi = 0; mi < 4; ++mi)
                #pragma unroll
                for (int ni = 0; ni < 4; ++ni)
                    acc[mi][ni] = __builtin_amdgcn_mfma_f32_16x16x32_bf16(
                        af[mi], bfr[ni], acc[mi][ni], 0, 0, 0);
        }
    };

    if (nt > 0) {
        STAGE(0, ks0);                       // 8 loads in flight (buf 0)
        int cur = 0;
        for (int ts = 0; ts < nt; ++ts) {
            if (ts + 1 < nt) {
                STAGE(cur ^ 1, ks0 + ts + 1);  // +8 (buf nxt) -> 16 outstanding
                asm volatile("s_waitcnt vmcnt(8)" ::: "memory"); // buf cur done
            } else {
                asm volatile("s_waitcnt vmcnt(0)" ::: "memory");
            }
            __builtin_amdgcn_s_barrier();
            __builtin_amdgcn_sched_barrier(0);
            COMPUTE(cur);
            __builtin_amdgcn_s_barrier();      // consumers done before overwrite
            __builtin_amdgcn_sched_barrier(0);
            cur ^= 1;
        }
    }

    // C: col = lane&15, row = (lane>>4)*4 + reg  (m89-verified); bf16 partials
    unsigned short* pbase = part + (size_t)blockIdx.z * M * N;
    #pragma unroll
    for (int mi = 0; mi < 4; ++mi) {
        #pragma unroll
        for (int ni = 0; ni < 4; ++ni) {
            int col = n0 + wc * 64 + ni * 16 + fr;
            if (col >= N) continue;
            #pragma unroll
            for (int j = 0; j < 4; ++j) {
                int row = m0 + wr * 64 + mi * 16 + fq * 4 + j;
                if (row < M) pbase[(size_t)row * N + col] = f2bf(acc[mi][ni][j]);
            }
        }
    }
}

// ------------------------------------------------- split-K MFMA bf16 GEMM 256x256
// 512 threads = 8 waves (2 x 4); each wave owns 128 x 64 output; counted vmcnt
__global__ __launch_bounds__(512, 2) void gemm256_bf16_kernel(
    const unsigned short* __restrict__ A, const unsigned short* __restrict__ B,
    unsigned short* __restrict__ part, int M, int N, int K, int ksteps, int KS)
{
    __shared__ unsigned short ldsA[2][256 * GBK];
    __shared__ unsigned short ldsB[2][256 * GBK];

    int t = threadIdx.x;
    int lane = t & 63, wave = t >> 6;      // 0..7
    int m0 = blockIdx.y * 256, n0 = blockIdx.x * 256;

    int steps_per = (ksteps + KS - 1) / KS;
    int ks0 = blockIdx.z * steps_per;
    int ks1 = min(ksteps, ks0 + steps_per);
    int nt = ks1 - ks0;

    int lrow  = lane >> 3;
    int lslot = (lane & 7) ^ lrow;
    const unsigned short* aSrc[4];
    const unsigned short* bSrc[4];
    #pragma unroll
    for (int i = 0; i < 4; ++i) {
        int r = wave * 32 + i * 8 + lrow;   // 8 waves x 32 rows = 256
        int gm = min(m0 + r, M - 1);
        int gn = min(n0 + r, N - 1);
        aSrc[i] = A + (size_t)gm * K + lslot * 8;
        bSrc[i] = B + (size_t)gn * K + lslot * 8;
    }

    int wr = wave >> 2, wc = wave & 3;     // 2 x 4 wave grid
    int fr = lane & 15, fq = lane >> 4;

    f32x4 acc[8][4] = {};

    auto STAGE = [&](int buf, int kt) {
        int koff = kt * GBK;
        #pragma unroll
        for (int i = 0; i < 4; ++i) {
            async16(&ldsA[buf][(wave * 32 + i * 8) * GBK], aSrc[i] + koff);
            async16(&ldsB[buf][(wave * 32 + i * 8) * GBK], bSrc[i] + koff);
        }
    };

    auto COMPUTE = [&](int buf) {
        #pragma unroll
        for (int h = 0; h < 2; ++h) {
            short8 af[8], bfr[4];
            #pragma unroll
            for (int mi = 0; mi < 8; ++mi) {
                int r = wr * 128 + mi * 16 + fr;
                int idx = r * GBK + (((h * 4 + fq) ^ (r & 7)) << 3);
                af[mi] = *(const short8*)&ldsA[buf][idx];
            }
            #pragma unroll
            for (int ni = 0; ni < 4; ++ni) {
                int r = wc * 64 + ni * 16 + fr;
                int idx = r * GBK + (((h * 4 + fq) ^ (r & 7)) << 3);
                bfr[ni] = *(const short8*)&ldsB[buf][idx];
            }
            #pragma unroll
            for (int mi = 0; mi < 8; ++mi)
                #pragma unroll
                for (int ni = 0; ni < 4; ++ni)
                    acc[mi][ni] = __builtin_amdgcn_mfma_f32_16x16x32_bf16(
                        af[mi], bfr[ni], acc[mi][ni], 0, 0, 0);
        }
    };

    if (nt > 0) {
        STAGE(0, ks0);
        int cur = 0;
        for (int ts = 0; ts < nt; ++ts) {
            if (ts + 1 < nt) {
                STAGE(cur ^ 1, ks0 + ts + 1);
                asm volatile("s_waitcnt vmcnt(8)" ::: "memory");
            } else {
                asm volatile("s_waitcnt vmcnt(0)" ::: "memory");
            }
            __builtin_amdgcn_s_barrier();
            __builtin_amdgcn_sched_barrier(0);
            COMPUTE(cur);
            __builtin_amdgcn_s_barrier();
            __builtin_amdgcn_sched_barrier(0);
            cur ^= 1;
        }
    }

    unsigned short* pbase = part + (size_t)blockIdx.z * M * N;
    #pragma unroll
    for (int mi = 0; mi < 8; ++mi) {
        #pragma unroll
        for (int ni = 0; ni < 4; ++ni) {
            int col = n0 + wc * 64 + ni * 16 + fr;
            if (col >= N) continue;
            #pragma unroll
            for (int j = 0; j < 4; ++j) {
                int row = m0 + wr * 128 + mi * 16 + fq * 4 + j;
                if (row < M) pbase[(size_t)row * N + col] = f2bf(acc[mi][ni][j]);
            }
        }
    }
}

// ------------------------- split-K reduce (bf16 partials) + bias (+relu)
__global__ __launch_bounds__(256) void reduce_kernel(
    const unsigned short* __restrict__ part, const float* __restrict__ bias,
    float* __restrict__ outf, unsigned short* __restrict__ outh,
    int M, int N, int KS, int relu)
{
    int idx = blockIdx.x * 256 + threadIdx.x;
    int tot = M * N;
    if (idx >= tot) return;
    int n = idx % N;
    float s = 0.f;
    for (int k = 0; k < KS; ++k) s += bf2f(part[(size_t)k * tot + idx]);
    s += bias[n];
    if (relu) s = fmaxf(s, 0.f);
    if (outf) outf[idx] = s;
    if (outh) outh[idx] = f2bf(s);
}

// ----------------- decode: block per ROI; wave0 softmax, wave d = reg dot d
__global__ __launch_bounds__(256) void decode_kernel(
    const float* __restrict__ cls, const float* __restrict__ x2buf,
    const float* __restrict__ reg_w, const float* __restrict__ reg_b,
    const float* __restrict__ props,
    float* __restrict__ scores, int* __restrict__ labels,
    float* __restrict__ boxes, int* __restrict__ valid,
    int n0, int rows, const int* __restrict__ img_h, const int* __restrict__ img_w)
{
    int rl = blockIdx.x;
    if (rl >= rows) return;
    int r = n0 + rl;
    int t = threadIdx.x;
    int lane = t & 63, wv = t >> 6;

    __shared__ float s_score;
    __shared__ int s_label;
    __shared__ float s_dsum[4];

    if (wv == 0) {
        float v0 = (lane < NCLS) ? cls[(size_t)r * NCLS + lane] : -INFINITY;
        float v1 = (lane + 64 < NCLS) ? cls[(size_t)r * NCLS + lane + 64] : -INFINITY;

        float mall = fmaxf(v0, v1);
        for (int s = 32; s; s >>= 1) mall = fmaxf(mall, __shfl_xor(mall, s));

        float bv = -INFINITY; int bi = 1 << 30;
        if (lane >= 1 && lane < NCLS) { bv = v0; bi = lane; }
        if (lane + 64 < NCLS && v1 > bv) { bv = v1; bi = lane + 64; }
        for (int s = 32; s; s >>= 1) {
            float ov = __shfl_xor(bv, s); int oi = __shfl_xor(bi, s);
            if (ov > bv || (ov == bv && oi < bi)) { bv = ov; bi = oi; }
        }

        float den = ((lane < NCLS) ? expf(v0 - mall) : 0.f) +
                    ((lane + 64 < NCLS) ? expf(v1 - mall) : 0.f);
        for (int s = 32; s; s >>= 1) den += __shfl_xor(den, s);

        if (lane == 0) {
            s_score = expf(bv - mall) / den;
            s_label = bi;
        }
    }
    __syncthreads();
    int label = s_label;

    {
        const float4* xr4 = (const float4*)(x2buf + (size_t)rl * HID);
        const float4* wr4 = (const float4*)(reg_w + (size_t)(label * 4 + wv) * HID);
        float4 a0 = xr4[lane],        b0 = wr4[lane];
        float4 a1 = xr4[lane + 64],   b1 = wr4[lane + 64];
        float4 a2 = xr4[lane + 128],  b2 = wr4[lane + 128];
        float4 a3 = xr4[lane + 192],  b3 = wr4[lane + 192];
        float sA = 0.f, sB = 0.f;
        sA = fmaf(a0.x, b0.x, sA); sA = fmaf(a0.y, b0.y, sA);
        sA = fmaf(a0.z, b0.z, sA); sA = fmaf(a0.w, b0.w, sA);
        sB = fmaf(a1.x, b1.x, sB); sB = fmaf(a1.y, b1.y, sB);
        sB = fmaf(a1.z, b1.z, sB); sB = fmaf(a1.w, b1.w, sB);
        sA = fmaf(a2.x, b2.x, sA); sA = fmaf(a2.y, b2.y, sA);
        sA = fmaf(a2.z, b2.z, sA); sA = fmaf(a2.w, b2.w, sA);
        sB = fmaf(a3.x, b3.x, sB); sB = fmaf(a3.y, b3.y, sB);
        sB = fmaf(a3.z, b3.z, sB); sB = fmaf(a3.w, b3.w, sB);
        float s = sA + sB;
        for (int sh = 32; sh; sh >>= 1) s += __shfl_xor(s, sh);
        if (lane == 0) s_dsum[wv] = s + reg_b[label * 4 + wv];
    }
    __syncthreads();

    if (t == 0) {
        float score = s_score;
        float p0 = props[r * 4 + 0], p1 = props[r * 4 + 1];
        float p2 = props[r * 4 + 2], p3 = props[r * 4 + 3];
        float pw = p2 - p0, ph = p3 - p1;
        float pcx = p0 + 0.5f * pw, pcy = p1 + 0.5f * ph;
        float dx = s_dsum[0], dy = s_dsum[1];
        float dw = fminf(s_dsum[2], DW_MAXF), dh = fminf(s_dsum[3], DW_MAXF);
        float cx = dx * pw + pcx, cy = dy * ph + pcy;
        float bw = expf(dw) * pw, bh = expf(dh) * ph;
        float iw = (float)img_w[0], ih = (float)img_h[0];
        float b0 = fminf(fmaxf(cx - 0.5f * bw, 0.f), iw);
        float b1 = fminf(fmaxf(cy - 0.5f * bh, 0.f), ih);
        float b2 = fminf(fmaxf(cx + 0.5f * bw, 0.f), iw);
        float b3 = fminf(fmaxf(cy + 0.5f * bh, 0.f), ih);
        boxes[r * 4 + 0] = b0; boxes[r * 4 + 1] = b1;
        boxes[r * 4 + 2] = b2; boxes[r * 4 + 3] = b3;
        scores[r] = score; labels[r] = label;
        valid[r] = (score >= 0.05f) && (b2 - b0 >= 1.f) && (b3 - b1 >= 1.f);
    }
}

// ------------------------- single-block max over boxes[0..4N) -> gmax (uint)
__global__ __launch_bounds__(1024) void gmax_kernel(
    const float* __restrict__ boxes, unsigned int* __restrict__ gmax, int total)
{
    int t = threadIdx.x;
    float m = -INFINITY;
    for (int i = t; i < total; i += 1024) m = fmaxf(m, boxes[i]);
    for (int s = 32; s; s >>= 1) m = fmaxf(m, __shfl_xor(m, s));
    __shared__ float wm[16];
    if ((t & 63) == 0) wm[t >> 6] = m;
    __syncthreads();
    if (t < 16) {
        float v = wm[t];
        for (int s = 8; s; s >>= 1) v = fmaxf(v, __shfl_xor(v, s));
        if (t == 0) gmax[0] = __float_as_uint(v);
    }
}

// ---------------------------------------- stable argsort via O(N^2) ranking
__global__ __launch_bounds__(256) void rank_kernel(
    const float* __restrict__ scores, const int* __restrict__ valid,
    int* __restrict__ order, int N)
{
    int i = blockIdx.x * 256 + threadIdx.x;
    __shared__ float sk[256];
    float ki = INFINITY;
    if (i < N && valid[i]) ki = -scores[i];
    int rank = 0;
    for (int j0 = 0; j0 < N; j0 += 256) {
        int j = j0 + threadIdx.x;
        float kj = INFINITY;
        if (j < N && valid[j]) kj = -scores[j];
        __syncthreads();
        sk[threadIdx.x] = kj;
        __syncthreads();
        int lim = min(256, N - j0);
        for (int jj = 0; jj < lim; ++jj) {
            float k2 = sk[jj];
            int jidx = j0 + jj;
            rank += (k2 < ki) || (k2 == ki && jidx < i);
        }
    }
    if (i < N) order[rank] = i;
}

// --------------------------------- gather sorted arrays + offset boxes + vcount
__global__ __launch_bounds__(256) void sortprep_kernel(
    const int* __restrict__ order, const float* __restrict__ boxes,
    const float* __restrict__ scores, const int* __restrict__ labels,
    const int* __restrict__ valid, const unsigned int* __restrict__ gmax,
    float* __restrict__ sob, float* __restrict__ sarea,
    float* __restrict__ sraw, float* __restrict__ ssc, int* __restrict__ slb,
    int* __restrict__ vcount, int N)
{
    int i = blockIdx.x * 256 + threadIdx.x;
    bool v = false;
    if (i < N) {
        int oi = order[i];
        float off = (float)labels[oi] * (__uint_as_float(gmax[0]) + 1.0f);
        float b0 = boxes[oi * 4 + 0] + off, b1 = boxes[oi * 4 + 1] + off;
        float b2 = boxes[oi * 4 + 2] + off, b3 = boxes[oi * 4 + 3] + off;
        sob[i * 4 + 0] = b0; sob[i * 4 + 1] = b1; sob[i * 4 + 2] = b2; sob[i * 4 + 3] = b3;
        sarea[i] = (b2 - b0) * (b3 - b1);
        sraw[i * 4 + 0] = boxes[oi * 4 + 0]; sraw[i * 4 + 1] = boxes[oi * 4 + 1];
        sraw[i * 4 + 2] = boxes[oi * 4 + 2]; sraw[i * 4 + 3] = boxes[oi * 4 + 3];
        ssc[i] = scores[oi]; slb[i] = labels[oi];
        v = valid[oi] != 0;
    }
    unsigned long long b = __ballot(v);
    if ((threadIdx.x & 63) == 0 && b)
        atomicAdd(vcount, __popcll(b));
}

// --------------------------- IoU>thresh bitmask (j > i), bounded by valid count
__global__ __launch_bounds__(256) void mask_kernel(
    const float* __restrict__ sob, const float* __restrict__ sarea,
    const int* __restrict__ vcount,
    unsigned long long* __restrict__ mask, int N, int NW)
{
    int V = vcount[0];
    int t = threadIdx.x;
    int w = t & 31, il = t >> 5;
    int i = blockIdx.x * 8 + il;
    if (i >= V || w >= NW) return;
    int jbase = w * 64;
    if (jbase >= V) return;
    float4 bi = *(const float4*)(sob + (size_t)i * 4);
    float ai = sarea[i];
    unsigned long long bits = 0;
    for (int b = 0; b < 64; ++b) {
        int j = jbase + b;
        if (j > i && j < V) {
            float4 bj = *(const float4*)(sob + (size_t)j * 4);
            float xl = fmaxf(bi.x, bj.x), yt = fmaxf(bi.y, bj.y);
            float xr = fminf(bi.z, bj.z), yb = fminf(bi.w, bj.w);
            float inter = fmaxf(xr - xl, 0.f) * fmaxf(yb - yt, 0.f);
            float iou = inter / (ai + sarea[j] - inter + 1e-9f);
            if (iou > 0.5f) bits |= 1ull << b;
        }
    }
    mask[(size_t)i * NW + w] = bits;
}

// ------------------- serial NMS scan over valid prefix, on-demand row loads
__global__ __launch_bounds__(64) void nms_kernel(
    const unsigned long long* __restrict__ mask,
    const int* __restrict__ vcount,
    const float* __restrict__ sraw, const float* __restrict__ ssc,
    const int* __restrict__ slb, float* __restrict__ out, int N, int NW)
{
    int V = vcount[0];
    int NWv = (V + 63) >> 6;
    int lane = threadIdx.x;
    unsigned long long supp = 0;
    int cnt = 0;
    for (int i = 0; i < V && cnt < TOPK_OUT; ++i) {
        int w = i >> 6, b = i & 63;
        unsigned long long sw = __shfl(supp, w);
        if (!((sw >> b) & 1ull)) {
            unsigned long long mi =
                (lane < NWv) ? mask[(size_t)i * NW + lane] : 0ull;
            supp |= mi;
            if (lane < 4) out[cnt * 4 + lane] = sraw[i * 4 + lane];
            if (lane == 4) out[4 * TOPK_OUT + cnt] = (float)slb[i];
            if (lane == 5) out[5 * TOPK_OUT + cnt] = ssc[i];
            cnt++;
        }
    }
    for (int s = cnt; s < TOPK_OUT; ++s) {
        if (lane < 4) out[s * 4 + lane] = 0.f;
        if (lane == 4) out[4 * TOPK_OUT + s] = 0.f;
        if (lane == 5) out[5 * TOPK_OUT + s] = 0.f;
    }
}

// --------------------------------------------------------------------------
extern "C" void kernel_launch(void* const* d_in, const int* in_sizes, int n_in,
                              void* d_out, int out_size, void* d_ws, size_t ws_size,
                              hipStream_t stream)
{
    const float* feat  = (const float*)d_in[0];
    const float* props = (const float*)d_in[1];
    const float* fc1_w = (const float*)d_in[2];
    const float* fc1_b = (const float*)d_in[3];
    const float* fc2_w = (const float*)d_in[4];
    const float* fc2_b = (const float*)d_in[5];
    const float* cls_w = (const float*)d_in[6];
    const float* cls_b = (const float*)d_in[7];
    const float* reg_w = (const float*)d_in[8];
    const float* reg_b = (const float*)d_in[9];
    const int* img_h = (const int*)d_in[10];
    const int* img_w = (const int*)d_in[11];
    float* out = (float*)d_out;

    int N = in_sizes[1] / 4;          // 2000
    int NW = (N + 63) >> 6;           // 32
    int n_fc1w = in_sizes[2];         // 12845056
    int n_fc2w = in_sizes[4];         // 1048576
    int n_clsw = in_sizes[6];         // 93184

    auto al = [](size_t x) { return (x + 255) & ~(size_t)255; };

    size_t miscBytes =
        al((size_t)FH * FW * FCH * 4) +               // featT f32
        al((size_t)N * NCLS * 4) +                    // cls
        al((size_t)N * 4) * 6 +                       // scores/labels/valid/order/sarea/ssc
        al((size_t)N * 16) * 3 +                      // boxes/sob/sraw
        al((size_t)N * 4) +                           // slb
        al(4) + al(4) +                               // vcount, gmax
        al((size_t)N * NW * 8);                       // mask
    size_t wBytes = al((size_t)n_fc1w * 2) + al((size_t)n_fc2w * 2) +
                    al((size_t)n_clsw * 2);

    size_t partCap = 32u << 20;       // 32 MB (bf16 partials)
    int chunk = N;
    auto need = [&](int ch, size_t pc) {
        return al(pc) + wBytes + miscBytes +
               al((size_t)ch * DIM * 2) +             // pooled bf16
               al((size_t)ch * HID * 2) +             // x1 bf16
               al((size_t)ch * HID * 4) +             // x2 f32
               al((size_t)ch * HID * 2);              // x2 bf16
    };
    while (need(chunk, partCap) > ws_size && chunk > 125) chunk = (chunk + 1) / 2;
    while (need(chunk, partCap) > ws_size && partCap > ((size_t)chunk * HID * 2 + (4u<<20)))
        partCap >>= 1;

    char* p = (char*)d_ws;
    auto grab = [&](size_t bytes) { char* q = p; p += al(bytes); return q; };
    unsigned short* part = (unsigned short*)grab(partCap);
    unsigned short* fc1wh = (unsigned short*)grab((size_t)n_fc1w * 2);
    unsigned short* fc2wh = (unsigned short*)grab((size_t)n_fc2w * 2);
    unsigned short* clswh = (unsigned short*)grab((size_t)n_clsw * 2);
    unsigned short* pooledh = (unsigned short*)grab((size_t)chunk * DIM * 2);
    unsigned short* x1h = (unsigned short*)grab((size_t)chunk * HID * 2);
    float* x2f = (float*)grab((size_t)chunk * HID * 4);
    unsigned short* x2h = (unsigned short*)grab((size_t)chunk * HID * 2);
    float* featT  = (float*)grab((size_t)FH * FW * FCH * 4);
    float* cls    = (float*)grab((size_t)N * NCLS * 4);
    float* scores = (float*)grab((size_t)N * 4);
    int*   labels = (int*)grab((size_t)N * 4);
    int*   valid  = (int*)grab((size_t)N * 4);
    float* boxes  = (float*)grab((size_t)N * 16);
    int*   order  = (int*)grab((size_t)N * 4);
    float* sob    = (float*)grab((size_t)N * 16);
    float* sarea  = (float*)grab((size_t)N * 4);
    float* sraw   = (float*)grab((size_t)N * 16);
    float* ssc    = (float*)grab((size_t)N * 4);
    int*   slb    = (int*)grab((size_t)N * 4);
    int*   vcount = (int*)grab(4);
    unsigned int* gmax = (unsigned int*)grab(4);
    unsigned long long* maskp = (unsigned long long*)grab((size_t)N * NW * 8);

    hipMemsetAsync(vcount, 0, 4, stream);

    // one-time: feature transpose (f32) + weight conversions
    {
        dim3 g(FCH / 64, (FH * FW + 63) / 64);
        ftrans_kernel<<<g, 256, 0, stream>>>(feat, featT);
    }
    wconv_perm_kernel<<<HID, 256, 0, stream>>>(fc1_w, fc1wh);
    wconv_kernel<<<(n_fc2w / 4 + 255) / 256, 256, 0, stream>>>(fc2_w, fc2wh, n_fc2w / 4);
    wconv_kernel<<<(n_clsw / 4 + 255) / 256, 256, 0, stream>>>(cls_w, clswh, n_clsw / 4);

    auto gemmb = [&](const unsigned short* Ah, const unsigned short* Bh,
                     const float* bias, float* outf, unsigned short* outh,
                     int M_, int N_, int K_, int relu) {
        bool big = (K_ >= 4096) && (N_ >= 256);      // FC1: 256x256 tiles
        int BT = big ? 256 : 128;
        int gm = (M_ + BT - 1) / BT;
        int gn = (N_ + BT - 1) / BT;
        int ksteps = K_ / GBK;
        int KS = (big ? 256 : 512) / (gm * gn);
        if (KS < 1) KS = 1;
        if (KS > 16) KS = 16;
        long ksMem = (long)(partCap / ((size_t)M_ * N_ * 2));
        if (KS > ksMem) KS = (int)ksMem;
        if (KS > ksteps) KS = ksteps;
        if (KS < 1) KS = 1;
        dim3 g(gn, gm, KS);
        if (big)
            gemm256_bf16_kernel<<<g, 512, 0, stream>>>(Ah, Bh, part, M_, N_, K_,
                                                       ksteps, KS);
        else
            gemm_bf16_kernel<<<g, 256, 0, stream>>>(Ah, Bh, part, M_, N_, K_,
                                                    ksteps, KS);
        int tot = M_ * N_;
        reduce_kernel<<<(tot + 255) / 256, 256, 0, stream>>>(part, bias, outf, outh,
                                                             M_, N_, KS, relu);
    };

    for (int n0 = 0; n0 < N; n0 += chunk) {
        int rows = min(chunk, N - n0);
        roi_pool_kernel<<<rows, 512, 0, stream>>>(
            featT, props, pooledh, n0, rows, img_h, img_w);
        gemmb(pooledh, fc1wh, fc1_b, nullptr, x1h, rows, HID, DIM, 1);
        gemmb(x1h, fc2wh, fc2_b, x2f, x2h, rows, HID, HID, 1);
        gemmb(x2h, clswh, cls_b, cls + (size_t)n0 * NCLS, nullptr, rows, NCLS, HID, 0);
        decode_kernel<<<rows, 256, 0, stream>>>(
            cls, x2f, reg_w, reg_b, props, scores, labels, boxes, valid,
            n0, rows, img_h, img_w);
    }

    gmax_kernel<<<1, 1024, 0, stream>>>(boxes, gmax, N * 4);
    rank_kernel<<<(N + 255) / 256, 256, 0, stream>>>(scores, valid, order, N);
    sortprep_kernel<<<(N + 255) / 256, 256, 0, stream>>>(
        order, boxes, scores, labels, valid, gmax, sob, sarea, sraw, ssc, slb,
        vcount, N);
    mask_kernel<<<(N + 7) / 8, 256, 0, stream>>>(sob, sarea, vcount, maskp, N, NW);
    nms_kernel<<<1, 64, 0, stream>>>(maskp, vcount, sraw, ssc, slb, out, N, NW);
}

// Round 12
// 364.463 us; speedup vs baseline: 1.0134x; 1.0134x over previous
//
#include <hip/hip_runtime.h>
#include <cstdint>

#define POOLK 7
#define NCLS 91
#define FH 50
#define FW 50
#define FCH 256
#define DIM (FCH * POOLK * POOLK) /* 12544 */
#define HID 1024
#define TOPK_OUT 100
#define DW_MAXF 4.135166556742356f

typedef __attribute__((ext_vector_type(8))) short short8;
typedef __attribute__((ext_vector_type(4))) float f32x4;

__device__ __forceinline__ unsigned short f2bf(float x)
{
    unsigned u = __float_as_uint(x);
    return (unsigned short)((u + 0x7FFFu + ((u >> 16) & 1u)) >> 16);
}
__device__ __forceinline__ float bf2f(unsigned short h)
{
    return __uint_as_float((unsigned)h << 16);
}

// XCD-chunked bijective block swizzle (guide T1 / m204): physical blocks with
// bid%8==i form XCD i's resident set; map them to a CONTIGUOUS logical chunk
// so panel-sharing tiles co-reside in one XCD's L2.
__device__ __forceinline__ int swz_linear(int gn, int gm, int gz)
{
    int nwg = gn * gm * gz;
    int bid = blockIdx.x + gn * (blockIdx.y + gm * blockIdx.z);
    if ((nwg & 7) == 0) {
        int cpx = nwg >> 3;
        return (bid & 7) * cpx + (bid >> 3);
    }
    return bid;
}

// ------------------------------- feat [C][2500] -> featT [2500][C] (f32)
__global__ __launch_bounds__(256) void ftrans_kernel(
    const float* __restrict__ feat, float* __restrict__ featT)
{
    __shared__ float tile[64][65];
    int c0 = blockIdx.x * 64;
    int p0 = blockIdx.y * 64;
    int lane = threadIdx.x & 63, r4 = threadIdx.x >> 6;
    #pragma unroll
    for (int r = r4; r < 64; r += 4) {
        int p = p0 + lane;
        if (p < FH * FW) tile[r][lane] = feat[(size_t)(c0 + r) * (FH * FW) + p];
    }
    __syncthreads();
    #pragma unroll
    for (int r = r4; r < 64; r += 4) {
        int p = p0 + r;
        if (p < FH * FW) featT[(size_t)p * FCH + c0 + lane] = tile[lane][r];
    }
}

// ---------------- ROI pool: block(512) per ROI, wave = cell, lane = 4 channels
__global__ __launch_bounds__(512) void roi_pool_kernel(
    const float* __restrict__ featT, const float* __restrict__ props,
    unsigned short* __restrict__ pooled, int n0, int rows,
    const int* __restrict__ img_h, const int* __restrict__ img_w)
{
    int rl = blockIdx.x;
    if (rl >= rows) return;
    int n = n0 + rl;
    int lane = threadIdx.x & 63;
    int wv = threadIdx.x >> 6;

    float scale = (float)fmin((double)FH / (double)img_h[0],
                              (double)FW / (double)img_w[0]);
    float x1 = rintf(props[n * 4 + 0] * scale);
    float y1 = rintf(props[n * 4 + 1] * scale);
    float x2 = rintf(props[n * 4 + 2] * scale);
    float y2 = rintf(props[n * 4 + 3] * scale);
    float roiw = fmaxf(x2 - x1 + 1.f, 1.f);
    float roih = fmaxf(y2 - y1 + 1.f, 1.f);

    const float4* ft4 = (const float4*)featT;
    unsigned short* orow = pooled + (size_t)rl * DIM;

    for (int cell = wv; cell < 49; cell += 8) {
        int py = cell / 7, px = cell - py * 7;
        int h0 = (int)fminf(fmaxf(floorf((float)py * roih / 7.f) + y1, 0.f), (float)FH);
        int h1 = (int)fminf(fmaxf(ceilf(((float)py + 1.f) * roih / 7.f) + y1, 0.f), (float)FH);
        int w0 = (int)fminf(fmaxf(floorf((float)px * roiw / 7.f) + x1, 0.f), (float)FW);
        int w1 = (int)fminf(fmaxf(ceilf(((float)px + 1.f) * roiw / 7.f) + x1, 0.f), (float)FW);

        float4 ma = make_float4(-INFINITY, -INFINITY, -INFINITY, -INFINITY);
        float4 mb = ma;
        for (int h = h0; h < h1; ++h) {
            const float4* rp = ft4 + (size_t)(h * FW) * 64 + lane;
            int w = w0;
            for (; w + 1 < w1; w += 2) {
                float4 va = rp[(size_t)w * 64];
                float4 vb = rp[(size_t)(w + 1) * 64];
                ma.x = fmaxf(ma.x, va.x); ma.y = fmaxf(ma.y, va.y);
                ma.z = fmaxf(ma.z, va.z); ma.w = fmaxf(ma.w, va.w);
                mb.x = fmaxf(mb.x, vb.x); mb.y = fmaxf(mb.y, vb.y);
                mb.z = fmaxf(mb.z, vb.z); mb.w = fmaxf(mb.w, vb.w);
            }
            if (w < w1) {
                float4 va = rp[(size_t)w * 64];
                ma.x = fmaxf(ma.x, va.x); ma.y = fmaxf(ma.y, va.y);
                ma.z = fmaxf(ma.z, va.z); ma.w = fmaxf(ma.w, va.w);
            }
        }
        float4 m;
        m.x = fmaxf(ma.x, mb.x); m.y = fmaxf(ma.y, mb.y);
        m.z = fmaxf(ma.z, mb.z); m.w = fmaxf(ma.w, mb.w);
        if (h0 >= h1 || w0 >= w1) m = make_float4(0.f, 0.f, 0.f, 0.f);
        ushort4 o;
        o.x = f2bf(m.x); o.y = f2bf(m.y); o.z = f2bf(m.z); o.w = f2bf(m.w);
        *(ushort4*)&orow[cell * FCH + lane * 4] = o;
    }
}

// --------------------------------------------------------- fp32 -> bf16 weights
__global__ __launch_bounds__(256) void wconv_kernel(
    const float* __restrict__ w, unsigned short* __restrict__ wh, int n4)
{
    int i = blockIdx.x * 256 + threadIdx.x;
    if (i >= n4) return;
    float4 v = ((const float4*)w)[i];
    ushort4 o;
    o.x = f2bf(v.x); o.y = f2bf(v.y); o.z = f2bf(v.z); o.w = f2bf(v.w);
    ((ushort4*)wh)[i] = o;
}

// ---- fc1_w conversion with K-permutation via LDS (coalesced both sides)
#define PERM_PAD 257
__global__ __launch_bounds__(256) void wconv_perm_kernel(
    const float* __restrict__ w, unsigned short* __restrict__ wh)
{
    __shared__ unsigned short sh[49 * PERM_PAD];
    int n = blockIdx.x;
    const float* row = w + (size_t)n * DIM;
    #pragma unroll 7
    for (int k = 0; k < 49; ++k) {
        int j = k * 256 + threadIdx.x;
        float v = row[j];
        int c = j / 49, cell = j - c * 49;
        sh[cell * PERM_PAD + c] = f2bf(v);
    }
    __syncthreads();
    unsigned short* orow = wh + (size_t)n * DIM;
    #pragma unroll 7
    for (int k = 0; k < 49; ++k) {
        int o = k * 256 + threadIdx.x;
        int cell = o >> 8, c = o & 255;
        orow[o] = sh[cell * PERM_PAD + c];
    }
}

typedef __attribute__((address_space(1))) void* gas_p;
typedef __attribute__((address_space(3))) void* las_p;
__device__ __forceinline__ void async16(void* l, const void* g)
{
    __builtin_amdgcn_global_load_lds((gas_p)g, (las_p)l, 16, 0, 0);
}

// ------------------------------------------------- split-K MFMA bf16 GEMM 128x128
#define GBK 64
__global__ __launch_bounds__(256, 2) void gemm_bf16_kernel(
    const unsigned short* __restrict__ A, const unsigned short* __restrict__ B,
    unsigned short* __restrict__ part, int M, int N, int K, int ksteps, int KS)
{
    __shared__ unsigned short ldsA[2][128 * GBK];
    __shared__ unsigned short ldsB[2][128 * GBK];

    int t = threadIdx.x;
    int lane = t & 63, wave = t >> 6;

    // XCD swizzle: logical tile from remapped linear id (n fastest)
    int gn = gridDim.x, gm = gridDim.y, gz = gridDim.z;
    int l = swz_linear(gn, gm, gz);
    int nb = l % gn, mb = (l / gn) % gm, zb = l / (gn * gm);
    int m0 = mb * 128, n0 = nb * 128;

    int steps_per = (ksteps + KS - 1) / KS;
    int ks0 = zb * steps_per;
    int ks1 = min(ksteps, ks0 + steps_per);
    int nt = ks1 - ks0;

    int lrow  = lane >> 3;
    int lslot = (lane & 7) ^ lrow;
    const unsigned short* aSrc[4];
    const unsigned short* bSrc[4];
    #pragma unroll
    for (int i = 0; i < 4; ++i) {
        int r = wave * 32 + i * 8 + lrow;
        int gmr = min(m0 + r, M - 1);
        int gnr = min(n0 + r, N - 1);
        aSrc[i] = A + (size_t)gmr * K + lslot * 8;
        bSrc[i] = B + (size_t)gnr * K + lslot * 8;
    }

    int wr = wave >> 1, wc = wave & 1;
    int fr = lane & 15, fq = lane >> 4;

    f32x4 acc[4][4] = {};

    auto STAGE = [&](int buf, int kt) {
        int koff = kt * GBK;
        #pragma unroll
        for (int i = 0; i < 4; ++i) {
            async16(&ldsA[buf][(wave * 32 + i * 8) * GBK], aSrc[i] + koff);
            async16(&ldsB[buf][(wave * 32 + i * 8) * GBK], bSrc[i] + koff);
        }
    };

    auto COMPUTE = [&](int buf) {
        #pragma unroll
        for (int h = 0; h < 2; ++h) {
            short8 af[4], bfr[4];
            #pragma unroll
            for (int mi = 0; mi < 4; ++mi) {
                int r = wr * 64 + mi * 16 + fr;
                int idx = r * GBK + (((h * 4 + fq) ^ (r & 7)) << 3);
                af[mi] = *(const short8*)&ldsA[buf][idx];
            }
            #pragma unroll
            for (int ni = 0; ni < 4; ++ni) {
                int r = wc * 64 + ni * 16 + fr;
                int idx = r * GBK + (((h * 4 + fq) ^ (r & 7)) << 3);
                bfr[ni] = *(const short8*)&ldsB[buf][idx];
            }
            #pragma unroll
            for (int mi = 0; mi < 4; ++mi)
                #pragma unroll
                for (int ni = 0; ni < 4; ++ni)
                    acc[mi][ni] = __builtin_amdgcn_mfma_f32_16x16x32_bf16(
                        af[mi], bfr[ni], acc[mi][ni], 0, 0, 0);
        }
    };

    if (nt > 0) {
        STAGE(0, ks0);
        int cur = 0;
        for (int ts = 0; ts < nt; ++ts) {
            if (ts + 1 < nt) {
                STAGE(cur ^ 1, ks0 + ts + 1);
                asm volatile("s_waitcnt vmcnt(8)" ::: "memory");
            } else {
                asm volatile("s_waitcnt vmcnt(0)" ::: "memory");
            }
            __builtin_amdgcn_s_barrier();
            __builtin_amdgcn_sched_barrier(0);
            COMPUTE(cur);
            __builtin_amdgcn_s_barrier();
            __builtin_amdgcn_sched_barrier(0);
            cur ^= 1;
        }
    }

    unsigned short* pbase = part + (size_t)zb * M * N;
    #pragma unroll
    for (int mi = 0; mi < 4; ++mi) {
        #pragma unroll
        for (int ni = 0; ni < 4; ++ni) {
            int col = n0 + wc * 64 + ni * 16 + fr;
            if (col >= N) continue;
            #pragma unroll
            for (int j = 0; j < 4; ++j) {
                int row = m0 + wr * 64 + mi * 16 + fq * 4 + j;
                if (row < M) pbase[(size_t)row * N + col] = f2bf(acc[mi][ni][j]);
            }
        }
    }
}

// ------------------------------------------------- split-K MFMA bf16 GEMM 256x256
__global__ __launch_bounds__(512, 2) void gemm256_bf16_kernel(
    const unsigned short* __restrict__ A, const unsigned short* __restrict__ B,
    unsigned short* __restrict__ part, int M, int N, int K, int ksteps, int KS)
{
    __shared__ unsigned short ldsA[2][256 * GBK];
    __shared__ unsigned short ldsB[2][256 * GBK];

    int t = threadIdx.x;
    int lane = t & 63, wave = t >> 6;

    int gn = gridDim.x, gm = gridDim.y, gz = gridDim.z;
    int l = swz_linear(gn, gm, gz);
    int nb = l % gn, mb = (l / gn) % gm, zb = l / (gn * gm);
    int m0 = mb * 256, n0 = nb * 256;

    int steps_per = (ksteps + KS - 1) / KS;
    int ks0 = zb * steps_per;
    int ks1 = min(ksteps, ks0 + steps_per);
    int nt = ks1 - ks0;

    int lrow  = lane >> 3;
    int lslot = (lane & 7) ^ lrow;
    const unsigned short* aSrc[4];
    const unsigned short* bSrc[4];
    #pragma unroll
    for (int i = 0; i < 4; ++i) {
        int r = wave * 32 + i * 8 + lrow;
        int gmr = min(m0 + r, M - 1);
        int gnr = min(n0 + r, N - 1);
        aSrc[i] = A + (size_t)gmr * K + lslot * 8;
        bSrc[i] = B + (size_t)gnr * K + lslot * 8;
    }

    int wr = wave >> 2, wc = wave & 3;
    int fr = lane & 15, fq = lane >> 4;

    f32x4 acc[8][4] = {};

    auto STAGE = [&](int buf, int kt) {
        int koff = kt * GBK;
        #pragma unroll
        for (int i = 0; i < 4; ++i) {
            async16(&ldsA[buf][(wave * 32 + i * 8) * GBK], aSrc[i] + koff);
            async16(&ldsB[buf][(wave * 32 + i * 8) * GBK], bSrc[i] + koff);
        }
    };

    auto COMPUTE = [&](int buf) {
        #pragma unroll
        for (int h = 0; h < 2; ++h) {
            short8 af[8], bfr[4];
            #pragma unroll
            for (int mi = 0; mi < 8; ++mi) {
                int r = wr * 128 + mi * 16 + fr;
                int idx = r * GBK + (((h * 4 + fq) ^ (r & 7)) << 3);
                af[mi] = *(const short8*)&ldsA[buf][idx];
            }
            #pragma unroll
            for (int ni = 0; ni < 4; ++ni) {
                int r = wc * 64 + ni * 16 + fr;
                int idx = r * GBK + (((h * 4 + fq) ^ (r & 7)) << 3);
                bfr[ni] = *(const short8*)&ldsB[buf][idx];
            }
            #pragma unroll
            for (int mi = 0; mi < 8; ++mi)
                #pragma unroll
                for (int ni = 0; ni < 4; ++ni)
                    acc[mi][ni] = __builtin_amdgcn_mfma_f32_16x16x32_bf16(
                        af[mi], bfr[ni], acc[mi][ni], 0, 0, 0);
        }
    };

    if (nt > 0) {
        STAGE(0, ks0);
        int cur = 0;
        for (int ts = 0; ts < nt; ++ts) {
            if (ts + 1 < nt) {
                STAGE(cur ^ 1, ks0 + ts + 1);
                asm volatile("s_waitcnt vmcnt(8)" ::: "memory");
            } else {
                asm volatile("s_waitcnt vmcnt(0)" ::: "memory");
            }
            __builtin_amdgcn_s_barrier();
            __builtin_amdgcn_sched_barrier(0);
            COMPUTE(cur);
            __builtin_amdgcn_s_barrier();
            __builtin_amdgcn_sched_barrier(0);
            cur ^= 1;
        }
    }

    unsigned short* pbase = part + (size_t)zb * M * N;
    #pragma unroll
    for (int mi = 0; mi < 8; ++mi) {
        #pragma unroll
        for (int ni = 0; ni < 4; ++ni) {
            int col = n0 + wc * 64 + ni * 16 + fr;
            if (col >= N) continue;
            #pragma unroll
            for (int j = 0; j < 4; ++j) {
                int row = m0 + wr * 128 + mi * 16 + fq * 4 + j;
                if (row < M) pbase[(size_t)row * N + col] = f2bf(acc[mi][ni][j]);
            }
        }
    }
}

// ------------------------- split-K reduce (bf16 partials) + bias (+relu)
__global__ __launch_bounds__(256) void reduce_kernel(
    const unsigned short* __restrict__ part, const float* __restrict__ bias,
    float* __restrict__ outf, unsigned short* __restrict__ outh,
    int M, int N, int KS, int relu)
{
    int idx = blockIdx.x * 256 + threadIdx.x;
    int tot = M * N;
    if (idx >= tot) return;
    int n = idx % N;
    float s = 0.f;
    for (int k = 0; k < KS; ++k) s += bf2f(part[(size_t)k * tot + idx]);
    s += bias[n];
    if (relu) s = fmaxf(s, 0.f);
    if (outf) outf[idx] = s;
    if (outh) outh[idx] = f2bf(s);
}

// ----------------- decode: block per ROI; wave0 softmax, wave d = reg dot d
__global__ __launch_bounds__(256) void decode_kernel(
    const float* __restrict__ cls, const float* __restrict__ x2buf,
    const float* __restrict__ reg_w, const float* __restrict__ reg_b,
    const float* __restrict__ props,
    float* __restrict__ scores, int* __restrict__ labels,
    float* __restrict__ boxes, int* __restrict__ valid,
    int n0, int rows, const int* __restrict__ img_h, const int* __restrict__ img_w)
{
    int rl = blockIdx.x;
    if (rl >= rows) return;
    int r = n0 + rl;
    int t = threadIdx.x;
    int lane = t & 63, wv = t >> 6;

    __shared__ float s_score;
    __shared__ int s_label;
    __shared__ float s_dsum[4];

    if (wv == 0) {
        float v0 = (lane < NCLS) ? cls[(size_t)r * NCLS + lane] : -INFINITY;
        float v1 = (lane + 64 < NCLS) ? cls[(size_t)r * NCLS + lane + 64] : -INFINITY;

        float mall = fmaxf(v0, v1);
        for (int s = 32; s; s >>= 1) mall = fmaxf(mall, __shfl_xor(mall, s));

        float bv = -INFINITY; int bi = 1 << 30;
        if (lane >= 1 && lane < NCLS) { bv = v0; bi = lane; }
        if (lane + 64 < NCLS && v1 > bv) { bv = v1; bi = lane + 64; }
        for (int s = 32; s; s >>= 1) {
            float ov = __shfl_xor(bv, s); int oi = __shfl_xor(bi, s);
            if (ov > bv || (ov == bv && oi < bi)) { bv = ov; bi = oi; }
        }

        float den = ((lane < NCLS) ? expf(v0 - mall) : 0.f) +
                    ((lane + 64 < NCLS) ? expf(v1 - mall) : 0.f);
        for (int s = 32; s; s >>= 1) den += __shfl_xor(den, s);

        if (lane == 0) {
            s_score = expf(bv - mall) / den;
            s_label = bi;
        }
    }
    __syncthreads();
    int label = s_label;

    {
        const float4* xr4 = (const float4*)(x2buf + (size_t)rl * HID);
        const float4* wr4 = (const float4*)(reg_w + (size_t)(label * 4 + wv) * HID);
        float4 a0 = xr4[lane],        b0 = wr4[lane];
        float4 a1 = xr4[lane + 64],   b1 = wr4[lane + 64];
        float4 a2 = xr4[lane + 128],  b2 = wr4[lane + 128];
        float4 a3 = xr4[lane + 192],  b3 = wr4[lane + 192];
        float sA = 0.f, sB = 0.f;
        sA = fmaf(a0.x, b0.x, sA); sA = fmaf(a0.y, b0.y, sA);
        sA = fmaf(a0.z, b0.z, sA); sA = fmaf(a0.w, b0.w, sA);
        sB = fmaf(a1.x, b1.x, sB); sB = fmaf(a1.y, b1.y, sB);
        sB = fmaf(a1.z, b1.z, sB); sB = fmaf(a1.w, b1.w, sB);
        sA = fmaf(a2.x, b2.x, sA); sA = fmaf(a2.y, b2.y, sA);
        sA = fmaf(a2.z, b2.z, sA); sA = fmaf(a2.w, b2.w, sA);
        sB = fmaf(a3.x, b3.x, sB); sB = fmaf(a3.y, b3.y, sB);
        sB = fmaf(a3.z, b3.z, sB); sB = fmaf(a3.w, b3.w, sB);
        float s = sA + sB;
        for (int sh = 32; sh; sh >>= 1) s += __shfl_xor(s, sh);
        if (lane == 0) s_dsum[wv] = s + reg_b[label * 4 + wv];
    }
    __syncthreads();

    if (t == 0) {
        float score = s_score;
        float p0 = props[r * 4 + 0], p1 = props[r * 4 + 1];
        float p2 = props[r * 4 + 2], p3 = props[r * 4 + 3];
        float pw = p2 - p0, ph = p3 - p1;
        float pcx = p0 + 0.5f * pw, pcy = p1 + 0.5f * ph;
        float dx = s_dsum[0], dy = s_dsum[1];
        float dw = fminf(s_dsum[2], DW_MAXF), dh = fminf(s_dsum[3], DW_MAXF);
        float cx = dx * pw + pcx, cy = dy * ph + pcy;
        float bw = expf(dw) * pw, bh = expf(dh) * ph;
        float iw = (float)img_w[0], ih = (float)img_h[0];
        float b0 = fminf(fmaxf(cx - 0.5f * bw, 0.f), iw);
        float b1 = fminf(fmaxf(cy - 0.5f * bh, 0.f), ih);
        float b2 = fminf(fmaxf(cx + 0.5f * bw, 0.f), iw);
        float b3 = fminf(fmaxf(cy + 0.5f * bh, 0.f), ih);
        boxes[r * 4 + 0] = b0; boxes[r * 4 + 1] = b1;
        boxes[r * 4 + 2] = b2; boxes[r * 4 + 3] = b3;
        scores[r] = score; labels[r] = label;
        valid[r] = (score >= 0.05f) && (b2 - b0 >= 1.f) && (b3 - b1 >= 1.f);
    }
}

// ------------------------- single-block max over boxes[0..4N) -> gmax (uint)
__global__ __launch_bounds__(1024) void gmax_kernel(
    const float* __restrict__ boxes, unsigned int* __restrict__ gmax, int total)
{
    int t = threadIdx.x;
    float m = -INFINITY;
    for (int i = t; i < total; i += 1024) m = fmaxf(m, boxes[i]);
    for (int s = 32; s; s >>= 1) m = fmaxf(m, __shfl_xor(m, s));
    __shared__ float wm[16];
    if ((t & 63) == 0) wm[t >> 6] = m;
    __syncthreads();
    if (t < 16) {
        float v = wm[t];
        for (int s = 8; s; s >>= 1) v = fmaxf(v, __shfl_xor(v, s));
        if (t == 0) gmax[0] = __float_as_uint(v);
    }
}

// ---------------------------------------- stable argsort via O(N^2) ranking
__global__ __launch_bounds__(256) void rank_kernel(
    const float* __restrict__ scores, const int* __restrict__ valid,
    int* __restrict__ order, int N)
{
    int i = blockIdx.x * 256 + threadIdx.x;
    __shared__ float sk[256];
    float ki = INFINITY;
    if (i < N && valid[i]) ki = -scores[i];
    int rank = 0;
    for (int j0 = 0; j0 < N; j0 += 256) {
        int j = j0 + threadIdx.x;
        float kj = INFINITY;
        if (j < N && valid[j]) kj = -scores[j];
        __syncthreads();
        sk[threadIdx.x] = kj;
        __syncthreads();
        int lim = min(256, N - j0);
        for (int jj = 0; jj < lim; ++jj) {
            float k2 = sk[jj];
            int jidx = j0 + jj;
            rank += (k2 < ki) || (k2 == ki && jidx < i);
        }
    }
    if (i < N) order[rank] = i;
}

// --------------------------------- gather sorted arrays + offset boxes + vcount
__global__ __launch_bounds__(256) void sortprep_kernel(
    const int* __restrict__ order, const float* __restrict__ boxes,
    const float* __restrict__ scores, const int* __restrict__ labels,
    const int* __restrict__ valid, const unsigned int* __restrict__ gmax,
    float* __restrict__ sob, float* __restrict__ sarea,
    float* __restrict__ sraw, float* __restrict__ ssc, int* __restrict__ slb,
    int* __restrict__ vcount, int N)
{
    int i = blockIdx.x * 256 + threadIdx.x;
    bool v = false;
    if (i < N) {
        int oi = order[i];
        float off = (float)labels[oi] * (__uint_as_float(gmax[0]) + 1.0f);
        float b0 = boxes[oi * 4 + 0] + off, b1 = boxes[oi * 4 + 1] + off;
        float b2 = boxes[oi * 4 + 2] + off, b3 = boxes[oi * 4 + 3] + off;
        sob[i * 4 + 0] = b0; sob[i * 4 + 1] = b1; sob[i * 4 + 2] = b2; sob[i * 4 + 3] = b3;
        sarea[i] = (b2 - b0) * (b3 - b1);
        sraw[i * 4 + 0] = boxes[oi * 4 + 0]; sraw[i * 4 + 1] = boxes[oi * 4 + 1];
        sraw[i * 4 + 2] = boxes[oi * 4 + 2]; sraw[i * 4 + 3] = boxes[oi * 4 + 3];
        ssc[i] = scores[oi]; slb[i] = labels[oi];
        v = valid[oi] != 0;
    }
    unsigned long long b = __ballot(v);
    if ((threadIdx.x & 63) == 0 && b)
        atomicAdd(vcount, __popcll(b));
}

// --------------------------- IoU>thresh bitmask (j > i), bounded by valid count
__global__ __launch_bounds__(256) void mask_kernel(
    const float* __restrict__ sob, const float* __restrict__ sarea,
    const int* __restrict__ vcount,
    unsigned long long* __restrict__ mask, int N, int NW)
{
    int V = vcount[0];
    int t = threadIdx.x;
    int w = t & 31, il = t >> 5;
    int i = blockIdx.x * 8 + il;
    if (i >= V || w >= NW) return;
    int jbase = w * 64;
    if (jbase >= V) return;
    float4 bi = *(const float4*)(sob + (size_t)i * 4);
    float ai = sarea[i];
    unsigned long long bits = 0;
    for (int b = 0; b < 64; ++b) {
        int j = jbase + b;
        if (j > i && j < V) {
            float4 bj = *(const float4*)(sob + (size_t)j * 4);
            float xl = fmaxf(bi.x, bj.x), yt = fmaxf(bi.y, bj.y);
            float xr = fminf(bi.z, bj.z), yb = fminf(bi.w, bj.w);
            float inter = fmaxf(xr - xl, 0.f) * fmaxf(yb - yt, 0.f);
            float iou = inter / (ai + sarea[j] - inter + 1e-9f);
            if (iou > 0.5f) bits |= 1ull << b;
        }
    }
    mask[(size_t)i * NW + w] = bits;
}

// ------------------- serial NMS scan over valid prefix, on-demand row loads
__global__ __launch_bounds__(64) void nms_kernel(
    const unsigned long long* __restrict__ mask,
    const int* __restrict__ vcount,
    const float* __restrict__ sraw, const float* __restrict__ ssc,
    const int* __restrict__ slb, float* __restrict__ out, int N, int NW)
{
    int V = vcount[0];
    int NWv = (V + 63) >> 6;
    int lane = threadIdx.x;
    unsigned long long supp = 0;
    int cnt = 0;
    for (int i = 0; i < V && cnt < TOPK_OUT; ++i) {
        int w = i >> 6, b = i & 63;
        unsigned long long sw = __shfl(supp, w);
        if (!((sw >> b) & 1ull)) {
            unsigned long long mi =
                (lane < NWv) ? mask[(size_t)i * NW + lane] : 0ull;
            supp |= mi;
            if (lane < 4) out[cnt * 4 + lane] = sraw[i * 4 + lane];
            if (lane == 4) out[4 * TOPK_OUT + cnt] = (float)slb[i];
            if (lane == 5) out[5 * TOPK_OUT + cnt] = ssc[i];
            cnt++;
        }
    }
    for (int s = cnt; s < TOPK_OUT; ++s) {
        if (lane < 4) out[s * 4 + lane] = 0.f;
        if (lane == 4) out[4 * TOPK_OUT + s] = 0.f;
        if (lane == 5) out[5 * TOPK_OUT + s] = 0.f;
    }
}

// --------------------------------------------------------------------------
extern "C" void kernel_launch(void* const* d_in, const int* in_sizes, int n_in,
                              void* d_out, int out_size, void* d_ws, size_t ws_size,
                              hipStream_t stream)
{
    const float* feat  = (const float*)d_in[0];
    const float* props = (const float*)d_in[1];
    const float* fc1_w = (const float*)d_in[2];
    const float* fc1_b = (const float*)d_in[3];
    const float* fc2_w = (const float*)d_in[4];
    const float* fc2_b = (const float*)d_in[5];
    const float* cls_w = (const float*)d_in[6];
    const float* cls_b = (const float*)d_in[7];
    const float* reg_w = (const float*)d_in[8];
    const float* reg_b = (const float*)d_in[9];
    const int* img_h = (const int*)d_in[10];
    const int* img_w = (const int*)d_in[11];
    float* out = (float*)d_out;

    int N = in_sizes[1] / 4;          // 2000
    int NW = (N + 63) >> 6;           // 32
    int n_fc1w = in_sizes[2];         // 12845056
    int n_fc2w = in_sizes[4];         // 1048576
    int n_clsw = in_sizes[6];         // 93184

    auto al = [](size_t x) { return (x + 255) & ~(size_t)255; };

    size_t miscBytes =
        al((size_t)FH * FW * FCH * 4) +
        al((size_t)N * NCLS * 4) +
        al((size_t)N * 4) * 6 +
        al((size_t)N * 16) * 3 +
        al((size_t)N * 4) +
        al(4) + al(4) +
        al((size_t)N * NW * 8);
    size_t wBytes = al((size_t)n_fc1w * 2) + al((size_t)n_fc2w * 2) +
                    al((size_t)n_clsw * 2);

    size_t partCap = 32u << 20;
    int chunk = N;
    auto need = [&](int ch, size_t pc) {
        return al(pc) + wBytes + miscBytes +
               al((size_t)ch * DIM * 2) +
               al((size_t)ch * HID * 2) +
               al((size_t)ch * HID * 4) +
               al((size_t)ch * HID * 2);
    };
    while (need(chunk, partCap) > ws_size && chunk > 125) chunk = (chunk + 1) / 2;
    while (need(chunk, partCap) > ws_size && partCap > ((size_t)chunk * HID * 2 + (4u<<20)))
        partCap >>= 1;

    char* p = (char*)d_ws;
    auto grab = [&](size_t bytes) { char* q = p; p += al(bytes); return q; };
    unsigned short* part = (unsigned short*)grab(partCap);
    unsigned short* fc1wh = (unsigned short*)grab((size_t)n_fc1w * 2);
    unsigned short* fc2wh = (unsigned short*)grab((size_t)n_fc2w * 2);
    unsigned short* clswh = (unsigned short*)grab((size_t)n_clsw * 2);
    unsigned short* pooledh = (unsigned short*)grab((size_t)chunk * DIM * 2);
    unsigned short* x1h = (unsigned short*)grab((size_t)chunk * HID * 2);
    float* x2f = (float*)grab((size_t)chunk * HID * 4);
    unsigned short* x2h = (unsigned short*)grab((size_t)chunk * HID * 2);
    float* featT  = (float*)grab((size_t)FH * FW * FCH * 4);
    float* cls    = (float*)grab((size_t)N * NCLS * 4);
    float* scores = (float*)grab((size_t)N * 4);
    int*   labels = (int*)grab((size_t)N * 4);
    int*   valid  = (int*)grab((size_t)N * 4);
    float* boxes  = (float*)grab((size_t)N * 16);
    int*   order  = (int*)grab((size_t)N * 4);
    float* sob    = (float*)grab((size_t)N * 16);
    float* sarea  = (float*)grab((size_t)N * 4);
    float* sraw   = (float*)grab((size_t)N * 16);
    float* ssc    = (float*)grab((size_t)N * 4);
    int*   slb    = (int*)grab((size_t)N * 4);
    int*   vcount = (int*)grab(4);
    unsigned int* gmax = (unsigned int*)grab(4);
    unsigned long long* maskp = (unsigned long long*)grab((size_t)N * NW * 8);

    hipMemsetAsync(vcount, 0, 4, stream);

    {
        dim3 g(FCH / 64, (FH * FW + 63) / 64);
        ftrans_kernel<<<g, 256, 0, stream>>>(feat, featT);
    }
    wconv_perm_kernel<<<HID, 256, 0, stream>>>(fc1_w, fc1wh);
    wconv_kernel<<<(n_fc2w / 4 + 255) / 256, 256, 0, stream>>>(fc2_w, fc2wh, n_fc2w / 4);
    wconv_kernel<<<(n_clsw / 4 + 255) / 256, 256, 0, stream>>>(cls_w, clswh, n_clsw / 4);

    auto gemmb = [&](const unsigned short* Ah, const unsigned short* Bh,
                     const float* bias, float* outf, unsigned short* outh,
                     int M_, int N_, int K_, int relu) {
        bool big = (K_ >= 4096) && (N_ >= 256);
        int BT = big ? 256 : 128;
        int gm = (M_ + BT - 1) / BT;
        int gn = (N_ + BT - 1) / BT;
        int ksteps = K_ / GBK;
        int KS = (big ? 256 : 512) / (gm * gn);
        if (KS < 1) KS = 1;
        if (KS > 16) KS = 16;
        long ksMem = (long)(partCap / ((size_t)M_ * N_ * 2));
        if (KS > ksMem) KS = (int)ksMem;
        if (KS > ksteps) KS = ksteps;
        if (KS < 1) KS = 1;
        dim3 g(gn, gm, KS);
        if (big)
            gemm256_bf16_kernel<<<g, 512, 0, stream>>>(Ah, Bh, part, M_, N_, K_,
                                                       ksteps, KS);
        else
            gemm_bf16_kernel<<<g, 256, 0, stream>>>(Ah, Bh, part, M_, N_, K_,
                                                    ksteps, KS);
        int tot = M_ * N_;
        reduce_kernel<<<(tot + 255) / 256, 256, 0, stream>>>(part, bias, outf, outh,
                                                             M_, N_, KS, relu);
    };

    for (int n0 = 0; n0 < N; n0 += chunk) {
        int rows = min(chunk, N - n0);
        roi_pool_kernel<<<rows, 512, 0, stream>>>(
            featT, props, pooledh, n0, rows, img_h, img_w);
        gemmb(pooledh, fc1wh, fc1_b, nullptr, x1h, rows, HID, DIM, 1);
        gemmb(x1h, fc2wh, fc2_b, x2f, x2h, rows, HID, HID, 1);
        gemmb(x2h, clswh, cls_b, cls + (size_t)n0 * NCLS, nullptr, rows, NCLS, HID, 0);
        decode_kernel<<<rows, 256, 0, stream>>>(
            cls, x2f, reg_w, reg_b, props, scores, labels, boxes, valid,
            n0, rows, img_h, img_w);
    }

    gmax_kernel<<<1, 1024, 0, stream>>>(boxes, gmax, N * 4);
    rank_kernel<<<(N + 255) / 256, 256, 0, stream>>>(scores, valid, order, N);
    sortprep_kernel<<<(N + 255) / 256, 256, 0, stream>>>(
        order, boxes, scores, labels, valid, gmax, sob, sarea, sraw, ssc, slb,
        vcount, N);
    mask_kernel<<<(N + 7) / 8, 256, 0, stream>>>(sob, sarea, vcount, maskp, N, NW);
    nms_kernel<<<1, 64, 0, stream>>>(maskp, vcount, sraw, ssc, slb, out, N, NW);
}